// Round 4
// baseline (538.188 us; speedup 1.0000x reference)
//
#include <hip/hip_runtime.h>
#include <math.h>
#include <float.h>

#define EPSBN 1e-5f

// ---------------- CSR build ----------------

__global__ void zero_two(int* __restrict__ a, int* __restrict__ b, int n) {
    int i = blockIdx.x * blockDim.x + threadIdx.x;
    if (i < n) { a[i] = 0; b[i] = 0; }
}

// XCD-partitioned degree count: block handles dst-range (blockIdx&7) over edge
// stripe (blockIdx>>3). All atomics for a given deg line come from one XCD
// (assuming blockIdx%8 -> XCD round-robin; correctness independent of mapping).
__global__ void count_deg_part(const int* __restrict__ dst, int* __restrict__ deg,
                               int E, int N, int S) {
    int part = blockIdx.x & 7;
    int stripe = blockIdx.x >> 3;
    int lo = (int)(((long long)N * part) >> 3);
    int hi = (int)(((long long)N * (part + 1)) >> 3);
    int chunk = (E + S - 1) / S;
    int e0 = stripe * chunk;
    int e1 = min(e0 + chunk, E);
    for (int e = e0 + (int)threadIdx.x; e < e1; e += blockDim.x) {
        int d = dst[e];
        if (d >= lo && d < hi) atomicAdd(&deg[d], 1);
    }
}

__global__ void calc_dinv(const int* __restrict__ deg, float* __restrict__ dinv, int N) {
    int i = blockIdx.x * blockDim.x + threadIdx.x;
    if (i < N) dinv[i] = 1.0f / sqrtf((float)deg[i] + 1.0f);
}

// per-256-block exclusive scan + block totals
__global__ void scanA(const int* __restrict__ deg, int* __restrict__ excl,
                      int* __restrict__ bsum, int N) {
    __shared__ int s[256];
    int i = blockIdx.x * 256 + threadIdx.x;
    int v = (i < N) ? deg[i] : 0;
    s[threadIdx.x] = v;
    __syncthreads();
    for (int off = 1; off < 256; off <<= 1) {
        int t = (threadIdx.x >= off) ? s[threadIdx.x - off] : 0;
        __syncthreads();
        s[threadIdx.x] += t;
        __syncthreads();
    }
    if (i < N) excl[i] = s[threadIdx.x] - v;
    if (threadIdx.x == 255) bsum[blockIdx.x] = s[255];
}

__global__ void scanB(const int* __restrict__ bsum, int* __restrict__ boff, int nb) {
    __shared__ int s[512];
    int v = ((int)threadIdx.x < nb) ? bsum[threadIdx.x] : 0;
    s[threadIdx.x] = v;
    __syncthreads();
    for (int off = 1; off < 512; off <<= 1) {
        int t = (threadIdx.x >= off) ? s[threadIdx.x - off] : 0;
        __syncthreads();
        s[threadIdx.x] += t;
        __syncthreads();
    }
    boff[threadIdx.x] = s[threadIdx.x] - v;
}

__global__ void scanC(int* __restrict__ offs, const int* __restrict__ boff, int N, int E) {
    int i = blockIdx.x * blockDim.x + threadIdx.x;
    if (i < N) offs[i] += boff[i >> 8];
    if (i == 0) offs[N] = E;
}

// XCD-partitioned scatter: csr lines for node-range r are written only by
// blocks with blockIdx%8==r -> one XCD owns each dirty line.
__global__ void scatter_edges_part(const int* __restrict__ src, const int* __restrict__ dst,
                                   const int* __restrict__ offs, int* __restrict__ cur,
                                   int* __restrict__ csr, int E, int N, int S) {
    int part = blockIdx.x & 7;
    int stripe = blockIdx.x >> 3;
    int lo = (int)(((long long)N * part) >> 3);
    int hi = (int)(((long long)N * (part + 1)) >> 3);
    int chunk = (E + S - 1) / S;
    int e0 = stripe * chunk;
    int e1 = min(e0 + chunk, E);
    for (int e = e0 + (int)threadIdx.x; e < e1; e += blockDim.x) {
        int d = dst[e];
        if (d >= lo && d < hi) {
            int p = offs[d] + atomicAdd(&cur[d], 1);
            csr[p] = src[e];
        }
    }
}

// ---------------- layer matmuls (epilogue: * dinv[node]) ----------------

// layer 0: x [N,3] @ W0 [3,64]
__global__ void mm_in3(const float* __restrict__ x, const float* __restrict__ W,
                       const float* __restrict__ dinv, float* __restrict__ hw, int N) {
    int t = blockIdx.x * blockDim.x + threadIdx.x;
    int n = t >> 6, f = t & 63;
    if (n < N) {
        float a = x[n * 3] * W[f] + x[n * 3 + 1] * W[64 + f] + x[n * 3 + 2] * W[128 + f];
        hw[t] = a * dinv[n];
    }
}

// layers 1,2: h [N,64] @ W [64,64]
// Register-resident W column per lane; h-row broadcast via v_readlane.
__global__ void mm64_reg(const float* __restrict__ h, const float* __restrict__ W,
                         const float* __restrict__ dinv, float* __restrict__ hw, int N) {
    int tid = threadIdx.x;
    int lane = tid & 63;
    int wave = blockIdx.x * (blockDim.x >> 6) + (tid >> 6);
    int nwaves = gridDim.x * (blockDim.x >> 6);

    float wcol[64];
#pragma unroll
    for (int k = 0; k < 64; k++) wcol[k] = W[k * 64 + lane];

    for (int n = wave; n < N; n += nwaves) {
        float hval = h[n * 64 + lane];
        float a0 = 0.f, a1 = 0.f, a2 = 0.f, a3 = 0.f;
#pragma unroll
        for (int k = 0; k < 64; k += 4) {
            float b0 = __int_as_float(__builtin_amdgcn_readlane(__float_as_int(hval), k));
            float b1 = __int_as_float(__builtin_amdgcn_readlane(__float_as_int(hval), k + 1));
            float b2 = __int_as_float(__builtin_amdgcn_readlane(__float_as_int(hval), k + 2));
            float b3 = __int_as_float(__builtin_amdgcn_readlane(__float_as_int(hval), k + 3));
            a0 += b0 * wcol[k];
            a1 += b1 * wcol[k + 1];
            a2 += b2 * wcol[k + 2];
            a3 += b3 * wcol[k + 3];
        }
        hw[n * 64 + lane] = ((a0 + a1) + (a2 + a3)) * dinv[n];
    }
}

// ---------------- aggregation + bias + BN + ReLU + residual ----------------
// One NODE per wave: c = lane>>4 walks every 4th edge, f4 = lane&15 holds a
// float4 of features. No degree divergence inside a wave; 8 gathers in flight
// (4 quarters x 2 unroll). Cross-lane shfl_xor(16,32) reduce at the end.

__device__ inline float4 shfl_xor_f4(float4 v, int mask) {
    float4 r;
    r.x = __shfl_xor(v.x, mask, 64);
    r.y = __shfl_xor(v.y, mask, 64);
    r.z = __shfl_xor(v.z, mask, 64);
    r.w = __shfl_xor(v.w, mask, 64);
    return r;
}

__global__ void agg_bn(const float4* __restrict__ hw, float4* __restrict__ h,
                       const float* __restrict__ dinv,
                       const int* __restrict__ csr, const int* __restrict__ offs,
                       const float4* __restrict__ bias4,
                       const float4* __restrict__ gamma4, const float4* __restrict__ beta4,
                       const float4* __restrict__ mean4, const float4* __restrict__ var4,
                       int residual, int N) {
    int tid = threadIdx.x;
    int lane = tid & 63;
    int c = lane >> 4;          // quarter-wave id: which edge slice
    int f4 = lane & 15;         // feature float4 index
    int n = blockIdx.x * 4 + (tid >> 6);
    if (n >= N) return;

    float4 a0 = make_float4(0.f, 0.f, 0.f, 0.f);
    float4 a1 = make_float4(0.f, 0.f, 0.f, 0.f);
    if (c == 0) a0 = hw[(size_t)n * 16 + f4];   // self-loop term (already * dinv[n])

    int e0 = offs[n], e1 = offs[n + 1];
    int e = e0 + c;
    while (e + 4 < e1) {
        int s0 = csr[e];
        int s1 = csr[e + 4];
        float4 v0 = hw[(size_t)s0 * 16 + f4];
        float4 v1 = hw[(size_t)s1 * 16 + f4];
        a0.x += v0.x; a0.y += v0.y; a0.z += v0.z; a0.w += v0.w;
        a1.x += v1.x; a1.y += v1.y; a1.z += v1.z; a1.w += v1.w;
        e += 8;
    }
    if (e < e1) {
        int s0 = csr[e];
        float4 v0 = hw[(size_t)s0 * 16 + f4];
        a0.x += v0.x; a0.y += v0.y; a0.z += v0.z; a0.w += v0.w;
    }
    float4 acc;
    acc.x = a0.x + a1.x; acc.y = a0.y + a1.y;
    acc.z = a0.z + a1.z; acc.w = a0.w + a1.w;

    // reduce across the 4 quarter-waves
    float4 t1 = shfl_xor_f4(acc, 16);
    acc.x += t1.x; acc.y += t1.y; acc.z += t1.z; acc.w += t1.w;
    float4 t2 = shfl_xor_f4(acc, 32);
    acc.x += t2.x; acc.y += t2.y; acc.z += t2.z; acc.w += t2.w;

    if (c == 0) {
        float di = dinv[n];
        float4 b = bias4[f4], g = gamma4[f4], bt = beta4[f4], mn = mean4[f4], vr = var4[f4];
        float4 r;
        r.x = fmaxf((acc.x * di + b.x - mn.x) * (1.0f / sqrtf(vr.x + EPSBN)) * g.x + bt.x, 0.f);
        r.y = fmaxf((acc.y * di + b.y - mn.y) * (1.0f / sqrtf(vr.y + EPSBN)) * g.y + bt.y, 0.f);
        r.z = fmaxf((acc.z * di + b.z - mn.z) * (1.0f / sqrtf(vr.z + EPSBN)) * g.z + bt.z, 0.f);
        r.w = fmaxf((acc.w * di + b.w - mn.w) * (1.0f / sqrtf(vr.w + EPSBN)) * g.w + bt.w, 0.f);
        if (residual) {
            float4 hp = h[(size_t)n * 16 + f4];
            r.x += hp.x; r.y += hp.y; r.z += hp.z; r.w += hp.w;
        }
        h[(size_t)n * 16 + f4] = r;
    }
}

// ---------------- pooling ----------------

__global__ void graph_ranges(const int* __restrict__ batch, int* __restrict__ gs,
                             int* __restrict__ ge, int N) {
    int i = blockIdx.x * blockDim.x + threadIdx.x;
    if (i >= N) return;
    int b = batch[i];
    if (i == 0 || batch[i - 1] != b) gs[b] = i;
    if (i == N - 1 || batch[i + 1] != b) ge[b] = i + 1;
}

__global__ void pool(const float4* __restrict__ h4, const int* __restrict__ gs,
                     const int* __restrict__ ge, float* __restrict__ pooled) {
    __shared__ float4 ssum[256], smax[256];
    int g = blockIdx.x;
    int tid = threadIdx.x;
    int f4 = tid & 15, c = tid >> 4;
    int s = gs[g], e = ge[g];
    float4 sum = make_float4(0.f, 0.f, 0.f, 0.f);
    float4 mx = make_float4(-FLT_MAX, -FLT_MAX, -FLT_MAX, -FLT_MAX);
    for (int i = s + c; i < e; i += 16) {
        float4 v = h4[(size_t)i * 16 + f4];
        sum.x += v.x; sum.y += v.y; sum.z += v.z; sum.w += v.w;
        mx.x = fmaxf(mx.x, v.x); mx.y = fmaxf(mx.y, v.y);
        mx.z = fmaxf(mx.z, v.z); mx.w = fmaxf(mx.w, v.w);
    }
    ssum[tid] = sum;
    smax[tid] = mx;
    __syncthreads();
    for (int half = 8; half >= 1; half >>= 1) {
        if (c < half) {
            int o = tid + half * 16;
            ssum[tid].x += ssum[o].x; ssum[tid].y += ssum[o].y;
            ssum[tid].z += ssum[o].z; ssum[tid].w += ssum[o].w;
            smax[tid].x = fmaxf(smax[tid].x, smax[o].x);
            smax[tid].y = fmaxf(smax[tid].y, smax[o].y);
            smax[tid].z = fmaxf(smax[tid].z, smax[o].z);
            smax[tid].w = fmaxf(smax[tid].w, smax[o].w);
        }
        __syncthreads();
    }
    if (c == 0) {
        float inv = 1.0f / (float)(e - s);
        float4 S = ssum[tid], M = smax[tid];
        float4 mean4 = make_float4(S.x * inv, S.y * inv, S.z * inv, S.w * inv);
        ((float4*)pooled)[(size_t)g * 32 + f4] = mean4;
        ((float4*)pooled)[(size_t)g * 32 + 16 + f4] = M;
    }
}

// ---------------- MLP head, fused per graph ----------------

__global__ void mlp(const float* __restrict__ pooled,
                    const float* __restrict__ W1, const float* __restrict__ b1,
                    const float* __restrict__ W2, const float* __restrict__ b2,
                    const float* __restrict__ Wg, const float* __restrict__ bg,
                    const float* __restrict__ Wb, const float* __restrict__ bb,
                    float* __restrict__ out) {
    __shared__ float in_s[128], h1[128], h2[64];
    int g = blockIdx.x, tid = threadIdx.x;
    in_s[tid] = pooled[g * 128 + tid];
    __syncthreads();
    float acc = b1[tid];
#pragma unroll 8
    for (int k = 0; k < 128; k++) acc += in_s[k] * W1[k * 128 + tid];
    h1[tid] = fmaxf(acc, 0.0f);
    __syncthreads();
    if (tid < 64) {
        float a2 = b2[tid];
#pragma unroll 8
        for (int k = 0; k < 128; k++) a2 += h1[k] * W2[k * 64 + tid];
        h2[tid] = fmaxf(a2, 0.0f);
    }
    __syncthreads();
    if (tid < 2) {
        const float* Wv = (tid == 0) ? Wg : Wb;
        float a = (tid == 0) ? bg[0] : bb[0];
        for (int k = 0; k < 64; k++) a += h2[k] * Wv[k];
        out[g * 2 + tid] = a;
    }
}

// ---------------- launch ----------------

extern "C" void kernel_launch(void* const* d_in, const int* in_sizes, int n_in,
                              void* d_out, int out_size, void* d_ws, size_t ws_size,
                              hipStream_t stream) {
    const float* x    = (const float*)d_in[0];
    const int*   ei   = (const int*)d_in[1];
    const int*   batch= (const int*)d_in[2];
    const float* W0   = (const float*)d_in[3];
    const float* b0   = (const float*)d_in[4];
    const float* Wh   = (const float*)d_in[5];
    const float* bh   = (const float*)d_in[6];
    const float* bng  = (const float*)d_in[7];
    const float* bnb  = (const float*)d_in[8];
    const float* bnm  = (const float*)d_in[9];
    const float* bnv  = (const float*)d_in[10];
    const float* fc1W = (const float*)d_in[11];
    const float* fc1b = (const float*)d_in[12];
    const float* fc2W = (const float*)d_in[13];
    const float* fc2b = (const float*)d_in[14];
    const float* fcgW = (const float*)d_in[15];
    const float* fcgb = (const float*)d_in[16];
    const float* fcbW = (const float*)d_in[17];
    const float* fcbb = (const float*)d_in[18];
    float* out = (float*)d_out;

    const int N = in_sizes[0] / 3;
    const int E = in_sizes[1] / 2;
    const int G = out_size / 2;
    const int* src = ei;
    const int* dst = ei + E;

    char* ws = (char*)d_ws;
    auto alloc = [&](size_t bytes) {
        char* p = ws;
        ws += (bytes + 255) & ~(size_t)255;
        return p;
    };
    int*   deg    = (int*)alloc((size_t)N * 4);
    int*   cur    = (int*)alloc((size_t)N * 4);
    float* dinv   = (float*)alloc((size_t)N * 4);
    int*   offs   = (int*)alloc((size_t)(N + 1) * 4);
    int*   bsum   = (int*)alloc(512 * 4);
    int*   boff   = (int*)alloc(512 * 4);
    int*   csr    = (int*)alloc((size_t)E * 4);
    float* h      = (float*)alloc((size_t)N * 64 * 4);
    float* hw     = (float*)alloc((size_t)N * 64 * 4);
    int*   gs     = (int*)alloc((size_t)G * 4);
    int*   ge     = (int*)alloc((size_t)G * 4);
    float* pooled = (float*)alloc((size_t)G * 128 * 4);

    const int B = 256;
    int nbScan = (N + 255) / 256;
    const int S = 512;                 // edge stripes per dst-range partition
    const int partBlocks = 8 * S;      // blockIdx&7 = dst-range, blockIdx>>3 = stripe

    zero_two<<<(N + B - 1) / B, B, 0, stream>>>(deg, cur, N);
    count_deg_part<<<partBlocks, B, 0, stream>>>(dst, deg, E, N, S);
    calc_dinv<<<(N + B - 1) / B, B, 0, stream>>>(deg, dinv, N);
    scanA<<<nbScan, 256, 0, stream>>>(deg, offs, bsum, N);
    scanB<<<1, 512, 0, stream>>>(bsum, boff, nbScan);
    scanC<<<(N + B - 1) / B, B, 0, stream>>>(offs, boff, N, E);
    scatter_edges_part<<<partBlocks, B, 0, stream>>>(src, dst, offs, cur, csr, E, N, S);

    int aggBlocks = (N + 3) / 4;       // one node per wave, 4 waves per block

    // layer 0
    mm_in3<<<((size_t)N * 64 + B - 1) / B, B, 0, stream>>>(x, W0, dinv, hw, N);
    agg_bn<<<aggBlocks, 256, 0, stream>>>((const float4*)hw, (float4*)h, dinv, csr, offs,
                                          (const float4*)b0,
                                          (const float4*)bng, (const float4*)bnb,
                                          (const float4*)bnm, (const float4*)bnv, 0, N);
    // layer 1
    mm64_reg<<<1024, 256, 0, stream>>>(h, Wh, dinv, hw, N);
    agg_bn<<<aggBlocks, 256, 0, stream>>>((const float4*)hw, (float4*)h, dinv, csr, offs,
                                          (const float4*)(bh),
                                          (const float4*)(bng + 64), (const float4*)(bnb + 64),
                                          (const float4*)(bnm + 64), (const float4*)(bnv + 64), 1, N);
    // layer 2
    mm64_reg<<<1024, 256, 0, stream>>>(h, Wh + 4096, dinv, hw, N);
    agg_bn<<<aggBlocks, 256, 0, stream>>>((const float4*)hw, (float4*)h, dinv, csr, offs,
                                          (const float4*)(bh + 64),
                                          (const float4*)(bng + 128), (const float4*)(bnb + 128),
                                          (const float4*)(bnm + 128), (const float4*)(bnv + 128), 1, N);

    // pooling + head
    graph_ranges<<<(N + B - 1) / B, B, 0, stream>>>(batch, gs, ge, N);
    pool<<<G, 256, 0, stream>>>((const float4*)h, gs, ge, pooled);
    mlp<<<G, 128, 0, stream>>>(pooled, fc1W, fc1b, fc2W, fc2b,
                               fcgW, fcgb, fcbW, fcbb, out);
}

// Round 5
// 529.698 us; speedup vs baseline: 1.0160x; 1.0160x over previous
//
#include <hip/hip_runtime.h>
#include <math.h>
#include <float.h>

#define EPSBN 1e-5f

// ---------------- CSR build ----------------

__global__ void zero_two(int* __restrict__ a, int* __restrict__ b, int n) {
    int i = blockIdx.x * blockDim.x + threadIdx.x;
    if (i < n) { a[i] = 0; b[i] = 0; }
}

// XCD-partitioned degree count. Streaming dst reads are non-temporal so the
// deg slice stays L2-resident on its owning XCD.
__global__ void count_deg_part(const int* __restrict__ dst, int* __restrict__ deg,
                               int E, int N, int S) {
    int part = blockIdx.x & 7;
    int stripe = blockIdx.x >> 3;
    int lo = (int)(((long long)N * part) >> 3);
    int hi = (int)(((long long)N * (part + 1)) >> 3);
    int chunk = (E + S - 1) / S;
    int e0 = stripe * chunk;
    int e1 = min(e0 + chunk, E);
    for (int e = e0 + (int)threadIdx.x; e < e1; e += blockDim.x) {
        int d = __builtin_nontemporal_load(dst + e);
        if (d >= lo && d < hi) atomicAdd(&deg[d], 1);
    }
}

__global__ void calc_dinv(const int* __restrict__ deg, float* __restrict__ dinv, int N) {
    int i = blockIdx.x * blockDim.x + threadIdx.x;
    if (i < N) dinv[i] = 1.0f / sqrtf((float)deg[i] + 1.0f);
}

// per-256-block exclusive scan + block totals
__global__ void scanA(const int* __restrict__ deg, int* __restrict__ excl,
                      int* __restrict__ bsum, int N) {
    __shared__ int s[256];
    int i = blockIdx.x * 256 + threadIdx.x;
    int v = (i < N) ? deg[i] : 0;
    s[threadIdx.x] = v;
    __syncthreads();
    for (int off = 1; off < 256; off <<= 1) {
        int t = (threadIdx.x >= off) ? s[threadIdx.x - off] : 0;
        __syncthreads();
        s[threadIdx.x] += t;
        __syncthreads();
    }
    if (i < N) excl[i] = s[threadIdx.x] - v;
    if (threadIdx.x == 255) bsum[blockIdx.x] = s[255];
}

__global__ void scanB(const int* __restrict__ bsum, int* __restrict__ boff, int nb) {
    __shared__ int s[512];
    int v = ((int)threadIdx.x < nb) ? bsum[threadIdx.x] : 0;
    s[threadIdx.x] = v;
    __syncthreads();
    for (int off = 1; off < 512; off <<= 1) {
        int t = (threadIdx.x >= off) ? s[threadIdx.x - off] : 0;
        __syncthreads();
        s[threadIdx.x] += t;
        __syncthreads();
    }
    boff[threadIdx.x] = s[threadIdx.x] - v;
}

__global__ void scanC(int* __restrict__ offs, const int* __restrict__ boff, int N, int E) {
    int i = blockIdx.x * blockDim.x + threadIdx.x;
    if (i < N) offs[i] += boff[i >> 8];
    if (i == 0) offs[N] = E;
}

// XCD-partitioned scatter: csr slice for node-range r is written only by
// blocks with blockIdx%8==r. Streaming src/dst reads are non-temporal so the
// 0.8 MB csr slice (plus cur/offs slices) stays L2-resident -> one writeback
// per csr line instead of one per store.
__global__ void scatter_edges_part(const int* __restrict__ src, const int* __restrict__ dst,
                                   const int* __restrict__ offs, int* __restrict__ cur,
                                   int* __restrict__ csr, int E, int N, int S) {
    int part = blockIdx.x & 7;
    int stripe = blockIdx.x >> 3;
    int lo = (int)(((long long)N * part) >> 3);
    int hi = (int)(((long long)N * (part + 1)) >> 3);
    int chunk = (E + S - 1) / S;
    int e0 = stripe * chunk;
    int e1 = min(e0 + chunk, E);
    for (int e = e0 + (int)threadIdx.x; e < e1; e += blockDim.x) {
        int d = __builtin_nontemporal_load(dst + e);
        if (d >= lo && d < hi) {
            int s = __builtin_nontemporal_load(src + e);
            int p = offs[d] + atomicAdd(&cur[d], 1);
            csr[p] = s;
        }
    }
}

// ---------------- layer matmuls (epilogue: * dinv[node]) ----------------

// layer 0: x [N,3] @ W0 [3,64]
__global__ void mm_in3(const float* __restrict__ x, const float* __restrict__ W,
                       const float* __restrict__ dinv, float* __restrict__ hw, int N) {
    int t = blockIdx.x * blockDim.x + threadIdx.x;
    int n = t >> 6, f = t & 63;
    if (n < N) {
        float a = x[n * 3] * W[f] + x[n * 3 + 1] * W[64 + f] + x[n * 3 + 2] * W[128 + f];
        hw[t] = a * dinv[n];
    }
}

// layers 1,2: h [N,64] @ W [64,64]
// Register-resident W column per lane; h-row broadcast via v_readlane.
__global__ void mm64_reg(const float* __restrict__ h, const float* __restrict__ W,
                         const float* __restrict__ dinv, float* __restrict__ hw, int N) {
    int tid = threadIdx.x;
    int lane = tid & 63;
    int wave = blockIdx.x * (blockDim.x >> 6) + (tid >> 6);
    int nwaves = gridDim.x * (blockDim.x >> 6);

    float wcol[64];
#pragma unroll
    for (int k = 0; k < 64; k++) wcol[k] = W[k * 64 + lane];

    for (int n = wave; n < N; n += nwaves) {
        float hval = h[n * 64 + lane];
        float a0 = 0.f, a1 = 0.f, a2 = 0.f, a3 = 0.f;
#pragma unroll
        for (int k = 0; k < 64; k += 4) {
            float b0 = __int_as_float(__builtin_amdgcn_readlane(__float_as_int(hval), k));
            float b1 = __int_as_float(__builtin_amdgcn_readlane(__float_as_int(hval), k + 1));
            float b2 = __int_as_float(__builtin_amdgcn_readlane(__float_as_int(hval), k + 2));
            float b3 = __int_as_float(__builtin_amdgcn_readlane(__float_as_int(hval), k + 3));
            a0 += b0 * wcol[k];
            a1 += b1 * wcol[k + 1];
            a2 += b2 * wcol[k + 2];
            a3 += b3 * wcol[k + 3];
        }
        hw[n * 64 + lane] = ((a0 + a1) + (a2 + a3)) * dinv[n];
    }
}

// ---------------- aggregation + bias + BN + ReLU + residual ----------------
// R2 winner: 16 lanes per node, float4 per lane, 4-edge unroll (4 gathers in flight).

__global__ void agg_bn(const float4* __restrict__ hw, float4* __restrict__ h,
                       const float* __restrict__ dinv,
                       const int* __restrict__ csr, const int* __restrict__ offs,
                       const float4* __restrict__ bias4,
                       const float4* __restrict__ gamma4, const float4* __restrict__ beta4,
                       const float4* __restrict__ mean4, const float4* __restrict__ var4,
                       int residual, int N) {
    int tid = threadIdx.x;
    int n = blockIdx.x * 16 + (tid >> 4);
    int f4 = tid & 15;
    if (n >= N) return;

    float4 a0 = hw[(size_t)n * 16 + f4];   // self-loop term (already * dinv[n])
    float4 a1 = make_float4(0.f, 0.f, 0.f, 0.f);
    float4 a2 = make_float4(0.f, 0.f, 0.f, 0.f);
    float4 a3 = make_float4(0.f, 0.f, 0.f, 0.f);

    int e0 = offs[n], e1 = offs[n + 1];
    int e = e0;
    for (; e + 4 <= e1; e += 4) {
        int s0 = csr[e], s1 = csr[e + 1], s2 = csr[e + 2], s3 = csr[e + 3];
        float4 v0 = hw[(size_t)s0 * 16 + f4];
        float4 v1 = hw[(size_t)s1 * 16 + f4];
        float4 v2 = hw[(size_t)s2 * 16 + f4];
        float4 v3 = hw[(size_t)s3 * 16 + f4];
        a0.x += v0.x; a0.y += v0.y; a0.z += v0.z; a0.w += v0.w;
        a1.x += v1.x; a1.y += v1.y; a1.z += v1.z; a1.w += v1.w;
        a2.x += v2.x; a2.y += v2.y; a2.z += v2.z; a2.w += v2.w;
        a3.x += v3.x; a3.y += v3.y; a3.z += v3.z; a3.w += v3.w;
    }
    for (; e < e1; e++) {
        int s = csr[e];
        float4 v = hw[(size_t)s * 16 + f4];
        a0.x += v.x; a0.y += v.y; a0.z += v.z; a0.w += v.w;
    }
    float4 acc;
    acc.x = (a0.x + a1.x) + (a2.x + a3.x);
    acc.y = (a0.y + a1.y) + (a2.y + a3.y);
    acc.z = (a0.z + a1.z) + (a2.z + a3.z);
    acc.w = (a0.w + a1.w) + (a2.w + a3.w);

    float di = dinv[n];
    float4 b = bias4[f4], g = gamma4[f4], bt = beta4[f4], mn = mean4[f4], vr = var4[f4];
    float4 r;
    r.x = fmaxf((acc.x * di + b.x - mn.x) * (1.0f / sqrtf(vr.x + EPSBN)) * g.x + bt.x, 0.f);
    r.y = fmaxf((acc.y * di + b.y - mn.y) * (1.0f / sqrtf(vr.y + EPSBN)) * g.y + bt.y, 0.f);
    r.z = fmaxf((acc.z * di + b.z - mn.z) * (1.0f / sqrtf(vr.z + EPSBN)) * g.z + bt.z, 0.f);
    r.w = fmaxf((acc.w * di + b.w - mn.w) * (1.0f / sqrtf(vr.w + EPSBN)) * g.w + bt.w, 0.f);
    if (residual) {
        float4 hp = h[(size_t)n * 16 + f4];
        r.x += hp.x; r.y += hp.y; r.z += hp.z; r.w += hp.w;
    }
    h[(size_t)n * 16 + f4] = r;
}

// ---------------- pooling ----------------

__global__ void graph_ranges(const int* __restrict__ batch, int* __restrict__ gs,
                             int* __restrict__ ge, int N) {
    int i = blockIdx.x * blockDim.x + threadIdx.x;
    if (i >= N) return;
    int b = batch[i];
    if (i == 0 || batch[i - 1] != b) gs[b] = i;
    if (i == N - 1 || batch[i + 1] != b) ge[b] = i + 1;
}

__global__ void pool(const float4* __restrict__ h4, const int* __restrict__ gs,
                     const int* __restrict__ ge, float* __restrict__ pooled) {
    __shared__ float4 ssum[256], smax[256];
    int g = blockIdx.x;
    int tid = threadIdx.x;
    int f4 = tid & 15, c = tid >> 4;
    int s = gs[g], e = ge[g];
    float4 sum = make_float4(0.f, 0.f, 0.f, 0.f);
    float4 mx = make_float4(-FLT_MAX, -FLT_MAX, -FLT_MAX, -FLT_MAX);
    for (int i = s + c; i < e; i += 16) {
        float4 v = h4[(size_t)i * 16 + f4];
        sum.x += v.x; sum.y += v.y; sum.z += v.z; sum.w += v.w;
        mx.x = fmaxf(mx.x, v.x); mx.y = fmaxf(mx.y, v.y);
        mx.z = fmaxf(mx.z, v.z); mx.w = fmaxf(mx.w, v.w);
    }
    ssum[tid] = sum;
    smax[tid] = mx;
    __syncthreads();
    for (int half = 8; half >= 1; half >>= 1) {
        if (c < half) {
            int o = tid + half * 16;
            ssum[tid].x += ssum[o].x; ssum[tid].y += ssum[o].y;
            ssum[tid].z += ssum[o].z; ssum[tid].w += ssum[o].w;
            smax[tid].x = fmaxf(smax[tid].x, smax[o].x);
            smax[tid].y = fmaxf(smax[tid].y, smax[o].y);
            smax[tid].z = fmaxf(smax[tid].z, smax[o].z);
            smax[tid].w = fmaxf(smax[tid].w, smax[o].w);
        }
        __syncthreads();
    }
    if (c == 0) {
        float inv = 1.0f / (float)(e - s);
        float4 S = ssum[tid], M = smax[tid];
        float4 mean4 = make_float4(S.x * inv, S.y * inv, S.z * inv, S.w * inv);
        ((float4*)pooled)[(size_t)g * 32 + f4] = mean4;
        ((float4*)pooled)[(size_t)g * 32 + 16 + f4] = M;
    }
}

// ---------------- MLP head, fused per graph ----------------

__global__ void mlp(const float* __restrict__ pooled,
                    const float* __restrict__ W1, const float* __restrict__ b1,
                    const float* __restrict__ W2, const float* __restrict__ b2,
                    const float* __restrict__ Wg, const float* __restrict__ bg,
                    const float* __restrict__ Wb, const float* __restrict__ bb,
                    float* __restrict__ out) {
    __shared__ float in_s[128], h1[128], h2[64];
    int g = blockIdx.x, tid = threadIdx.x;
    in_s[tid] = pooled[g * 128 + tid];
    __syncthreads();
    float acc = b1[tid];
#pragma unroll 8
    for (int k = 0; k < 128; k++) acc += in_s[k] * W1[k * 128 + tid];
    h1[tid] = fmaxf(acc, 0.0f);
    __syncthreads();
    if (tid < 64) {
        float a2 = b2[tid];
#pragma unroll 8
        for (int k = 0; k < 128; k++) a2 += h1[k] * W2[k * 64 + tid];
        h2[tid] = fmaxf(a2, 0.0f);
    }
    __syncthreads();
    if (tid < 2) {
        const float* Wv = (tid == 0) ? Wg : Wb;
        float a = (tid == 0) ? bg[0] : bb[0];
        for (int k = 0; k < 64; k++) a += h2[k] * Wv[k];
        out[g * 2 + tid] = a;
    }
}

// ---------------- launch ----------------

extern "C" void kernel_launch(void* const* d_in, const int* in_sizes, int n_in,
                              void* d_out, int out_size, void* d_ws, size_t ws_size,
                              hipStream_t stream) {
    const float* x    = (const float*)d_in[0];
    const int*   ei   = (const int*)d_in[1];
    const int*   batch= (const int*)d_in[2];
    const float* W0   = (const float*)d_in[3];
    const float* b0   = (const float*)d_in[4];
    const float* Wh   = (const float*)d_in[5];
    const float* bh   = (const float*)d_in[6];
    const float* bng  = (const float*)d_in[7];
    const float* bnb  = (const float*)d_in[8];
    const float* bnm  = (const float*)d_in[9];
    const float* bnv  = (const float*)d_in[10];
    const float* fc1W = (const float*)d_in[11];
    const float* fc1b = (const float*)d_in[12];
    const float* fc2W = (const float*)d_in[13];
    const float* fc2b = (const float*)d_in[14];
    const float* fcgW = (const float*)d_in[15];
    const float* fcgb = (const float*)d_in[16];
    const float* fcbW = (const float*)d_in[17];
    const float* fcbb = (const float*)d_in[18];
    float* out = (float*)d_out;

    const int N = in_sizes[0] / 3;
    const int E = in_sizes[1] / 2;
    const int G = out_size / 2;
    const int* src = ei;
    const int* dst = ei + E;

    char* ws = (char*)d_ws;
    auto alloc = [&](size_t bytes) {
        char* p = ws;
        ws += (bytes + 255) & ~(size_t)255;
        return p;
    };
    int*   deg    = (int*)alloc((size_t)N * 4);
    int*   cur    = (int*)alloc((size_t)N * 4);
    float* dinv   = (float*)alloc((size_t)N * 4);
    int*   offs   = (int*)alloc((size_t)(N + 1) * 4);
    int*   bsum   = (int*)alloc(512 * 4);
    int*   boff   = (int*)alloc(512 * 4);
    int*   csr    = (int*)alloc((size_t)E * 4);
    float* h      = (float*)alloc((size_t)N * 64 * 4);
    float* hw     = (float*)alloc((size_t)N * 64 * 4);
    int*   gs     = (int*)alloc((size_t)G * 4);
    int*   ge     = (int*)alloc((size_t)G * 4);
    float* pooled = (float*)alloc((size_t)G * 128 * 4);

    const int B = 256;
    int nbScan = (N + 255) / 256;
    const int S = 512;                 // edge stripes per dst-range partition
    const int partBlocks = 8 * S;      // blockIdx&7 = dst-range, blockIdx>>3 = stripe

    zero_two<<<(N + B - 1) / B, B, 0, stream>>>(deg, cur, N);
    count_deg_part<<<partBlocks, B, 0, stream>>>(dst, deg, E, N, S);
    calc_dinv<<<(N + B - 1) / B, B, 0, stream>>>(deg, dinv, N);
    scanA<<<nbScan, 256, 0, stream>>>(deg, offs, bsum, N);
    scanB<<<1, 512, 0, stream>>>(bsum, boff, nbScan);
    scanC<<<(N + B - 1) / B, B, 0, stream>>>(offs, boff, N, E);
    scatter_edges_part<<<partBlocks, B, 0, stream>>>(src, dst, offs, cur, csr, E, N, S);

    int aggBlocks = (N + 15) / 16;     // 16 nodes per block (16 lanes/node)

    // layer 0
    mm_in3<<<((size_t)N * 64 + B - 1) / B, B, 0, stream>>>(x, W0, dinv, hw, N);
    agg_bn<<<aggBlocks, 256, 0, stream>>>((const float4*)hw, (float4*)h, dinv, csr, offs,
                                          (const float4*)b0,
                                          (const float4*)bng, (const float4*)bnb,
                                          (const float4*)bnm, (const float4*)bnv, 0, N);
    // layer 1
    mm64_reg<<<1024, 256, 0, stream>>>(h, Wh, dinv, hw, N);
    agg_bn<<<aggBlocks, 256, 0, stream>>>((const float4*)hw, (float4*)h, dinv, csr, offs,
                                          (const float4*)(bh),
                                          (const float4*)(bng + 64), (const float4*)(bnb + 64),
                                          (const float4*)(bnm + 64), (const float4*)(bnv + 64), 1, N);
    // layer 2
    mm64_reg<<<1024, 256, 0, stream>>>(h, Wh + 4096, dinv, hw, N);
    agg_bn<<<aggBlocks, 256, 0, stream>>>((const float4*)hw, (float4*)h, dinv, csr, offs,
                                          (const float4*)(bh + 64),
                                          (const float4*)(bng + 128), (const float4*)(bnb + 128),
                                          (const float4*)(bnm + 128), (const float4*)(bnv + 128), 1, N);

    // pooling + head
    graph_ranges<<<(N + B - 1) / B, B, 0, stream>>>(batch, gs, ge, N);
    pool<<<G, 256, 0, stream>>>((const float4*)h, gs, ge, pooled);
    mlp<<<G, 128, 0, stream>>>(pooled, fc1W, fc1b, fc2W, fc2b,
                               fcgW, fcgb, fcbW, fcbb, out);
}

// Round 6
// 467.047 us; speedup vs baseline: 1.1523x; 1.1341x over previous
//
#include <hip/hip_runtime.h>
#include <hip/hip_fp16.h>
#include <math.h>
#include <float.h>

#define EPSBN 1e-5f

// ---------------- CSR build ----------------

__global__ void zero_two(int* __restrict__ a, int* __restrict__ b, int n) {
    int i = blockIdx.x * blockDim.x + threadIdx.x;
    if (i < n) { a[i] = 0; b[i] = 0; }
}

// XCD-partitioned degree count, int4-vectorized scan.
// chunk is a multiple of 4 and E % 4 == 0, so no scalar tail is needed.
__global__ void count_deg_part(const int* __restrict__ dst, int* __restrict__ deg,
                               int E, int N, int S) {
    int part = blockIdx.x & 7;
    int stripe = blockIdx.x >> 3;
    int lo = (int)(((long long)N * part) >> 3);
    int hi = (int)(((long long)N * (part + 1)) >> 3);
    int chunk = (((E + S - 1) / S) + 3) & ~3;
    int e0 = stripe * chunk;
    int e1 = min(e0 + chunk, E);
    for (int e = e0 + (int)threadIdx.x * 4; e + 4 <= e1; e += blockDim.x * 4) {
        int4 d4 = *(const int4*)(dst + e);
        if (d4.x >= lo && d4.x < hi) atomicAdd(&deg[d4.x], 1);
        if (d4.y >= lo && d4.y < hi) atomicAdd(&deg[d4.y], 1);
        if (d4.z >= lo && d4.z < hi) atomicAdd(&deg[d4.z], 1);
        if (d4.w >= lo && d4.w < hi) atomicAdd(&deg[d4.w], 1);
    }
}

__global__ void calc_dinv(const int* __restrict__ deg, float* __restrict__ dinv, int N) {
    int i = blockIdx.x * blockDim.x + threadIdx.x;
    if (i < N) dinv[i] = 1.0f / sqrtf((float)deg[i] + 1.0f);
}

// per-256-block exclusive scan + block totals
__global__ void scanA(const int* __restrict__ deg, int* __restrict__ excl,
                      int* __restrict__ bsum, int N) {
    __shared__ int s[256];
    int i = blockIdx.x * 256 + threadIdx.x;
    int v = (i < N) ? deg[i] : 0;
    s[threadIdx.x] = v;
    __syncthreads();
    for (int off = 1; off < 256; off <<= 1) {
        int t = (threadIdx.x >= off) ? s[threadIdx.x - off] : 0;
        __syncthreads();
        s[threadIdx.x] += t;
        __syncthreads();
    }
    if (i < N) excl[i] = s[threadIdx.x] - v;
    if (threadIdx.x == 255) bsum[blockIdx.x] = s[255];
}

__global__ void scanB(const int* __restrict__ bsum, int* __restrict__ boff, int nb) {
    __shared__ int s[512];
    int v = ((int)threadIdx.x < nb) ? bsum[threadIdx.x] : 0;
    s[threadIdx.x] = v;
    __syncthreads();
    for (int off = 1; off < 512; off <<= 1) {
        int t = (threadIdx.x >= off) ? s[threadIdx.x - off] : 0;
        __syncthreads();
        s[threadIdx.x] += t;
        __syncthreads();
    }
    boff[threadIdx.x] = s[threadIdx.x] - v;
}

__global__ void scanC(int* __restrict__ offs, const int* __restrict__ boff, int N, int E) {
    int i = blockIdx.x * blockDim.x + threadIdx.x;
    if (i < N) offs[i] += boff[i >> 8];
    if (i == 0) offs[N] = E;
}

// XCD-partitioned scatter, int4-vectorized scan (plain loads; nt regressed).
__global__ void scatter_edges_part(const int* __restrict__ src, const int* __restrict__ dst,
                                   const int* __restrict__ offs, int* __restrict__ cur,
                                   int* __restrict__ csr, int E, int N, int S) {
    int part = blockIdx.x & 7;
    int stripe = blockIdx.x >> 3;
    int lo = (int)(((long long)N * part) >> 3);
    int hi = (int)(((long long)N * (part + 1)) >> 3);
    int chunk = (((E + S - 1) / S) + 3) & ~3;
    int e0 = stripe * chunk;
    int e1 = min(e0 + chunk, E);
    for (int e = e0 + (int)threadIdx.x * 4; e + 4 <= e1; e += blockDim.x * 4) {
        int4 d4 = *(const int4*)(dst + e);
        int4 s4 = *(const int4*)(src + e);
        if (d4.x >= lo && d4.x < hi) { int p = offs[d4.x] + atomicAdd(&cur[d4.x], 1); csr[p] = s4.x; }
        if (d4.y >= lo && d4.y < hi) { int p = offs[d4.y] + atomicAdd(&cur[d4.y], 1); csr[p] = s4.y; }
        if (d4.z >= lo && d4.z < hi) { int p = offs[d4.z] + atomicAdd(&cur[d4.z], 1); csr[p] = s4.z; }
        if (d4.w >= lo && d4.w < hi) { int p = offs[d4.w] + atomicAdd(&cur[d4.w], 1); csr[p] = s4.w; }
    }
}

// ---------------- layer matmuls (epilogue: * dinv[node], pack to fp16) ----------------

// layer 0: x [N,3] @ W0 [3,64] -> hw (fp16)
__global__ void mm_in3(const float* __restrict__ x, const float* __restrict__ W,
                       const float* __restrict__ dinv, __half* __restrict__ hw, int N) {
    int t = blockIdx.x * blockDim.x + threadIdx.x;
    int n = t >> 6, f = t & 63;
    if (n < N) {
        float a = x[n * 3] * W[f] + x[n * 3 + 1] * W[64 + f] + x[n * 3 + 2] * W[128 + f];
        a *= dinv[n];
        float other = __shfl_xor(a, 1, 64);
        if (!(f & 1)) ((__half2*)hw)[t >> 1] = __floats2half2_rn(a, other);
    }
}

// layers 1,2: h [N,64] @ W [64,64] -> hw (fp16)
// Register-resident W column per lane; h-row broadcast via v_readlane.
__global__ void mm64_reg(const float* __restrict__ h, const float* __restrict__ W,
                         const float* __restrict__ dinv, __half* __restrict__ hw, int N) {
    int tid = threadIdx.x;
    int lane = tid & 63;
    int wave = blockIdx.x * (blockDim.x >> 6) + (tid >> 6);
    int nwaves = gridDim.x * (blockDim.x >> 6);

    float wcol[64];
#pragma unroll
    for (int k = 0; k < 64; k++) wcol[k] = W[k * 64 + lane];

    for (int n = wave; n < N; n += nwaves) {
        float hval = h[n * 64 + lane];
        float a0 = 0.f, a1 = 0.f, a2 = 0.f, a3 = 0.f;
#pragma unroll
        for (int k = 0; k < 64; k += 4) {
            float b0 = __int_as_float(__builtin_amdgcn_readlane(__float_as_int(hval), k));
            float b1 = __int_as_float(__builtin_amdgcn_readlane(__float_as_int(hval), k + 1));
            float b2 = __int_as_float(__builtin_amdgcn_readlane(__float_as_int(hval), k + 2));
            float b3 = __int_as_float(__builtin_amdgcn_readlane(__float_as_int(hval), k + 3));
            a0 += b0 * wcol[k];
            a1 += b1 * wcol[k + 1];
            a2 += b2 * wcol[k + 2];
            a3 += b3 * wcol[k + 3];
        }
        float res = ((a0 + a1) + (a2 + a3)) * dinv[n];
        float other = __shfl_xor(res, 1, 64);
        if (!(lane & 1))
            ((__half2*)hw)[((size_t)n * 64 + lane) >> 1] = __floats2half2_rn(res, other);
    }
}

// ---------------- aggregation + bias + BN + ReLU + residual ----------------
// 16 lanes per node; each lane gathers 4 fp16 features (8 B, uint2) per edge;
// 4-edge unroll keeps 4 gathers in flight. Accumulation in fp32.

__device__ inline float4 h4_to_f4(uint2 r) {
    __half2 a = *(__half2*)&r.x;
    __half2 b = *(__half2*)&r.y;
    float2 fa = __half22float2(a), fb = __half22float2(b);
    return make_float4(fa.x, fa.y, fb.x, fb.y);
}

__global__ void agg_bn(const uint2* __restrict__ hw2, float4* __restrict__ h,
                       const float* __restrict__ dinv,
                       const int* __restrict__ csr, const int* __restrict__ offs,
                       const float4* __restrict__ bias4,
                       const float4* __restrict__ gamma4, const float4* __restrict__ beta4,
                       const float4* __restrict__ mean4, const float4* __restrict__ var4,
                       int residual, int N) {
    int tid = threadIdx.x;
    int n = blockIdx.x * 16 + (tid >> 4);
    int f4 = tid & 15;
    if (n >= N) return;

    float4 a0 = h4_to_f4(hw2[(size_t)n * 16 + f4]);   // self-loop term (already * dinv[n])
    float4 a1 = make_float4(0.f, 0.f, 0.f, 0.f);
    float4 a2 = make_float4(0.f, 0.f, 0.f, 0.f);
    float4 a3 = make_float4(0.f, 0.f, 0.f, 0.f);

    int e0 = offs[n], e1 = offs[n + 1];
    int e = e0;
    for (; e + 4 <= e1; e += 4) {
        int s0 = csr[e], s1 = csr[e + 1], s2 = csr[e + 2], s3 = csr[e + 3];
        float4 v0 = h4_to_f4(hw2[(size_t)s0 * 16 + f4]);
        float4 v1 = h4_to_f4(hw2[(size_t)s1 * 16 + f4]);
        float4 v2 = h4_to_f4(hw2[(size_t)s2 * 16 + f4]);
        float4 v3 = h4_to_f4(hw2[(size_t)s3 * 16 + f4]);
        a0.x += v0.x; a0.y += v0.y; a0.z += v0.z; a0.w += v0.w;
        a1.x += v1.x; a1.y += v1.y; a1.z += v1.z; a1.w += v1.w;
        a2.x += v2.x; a2.y += v2.y; a2.z += v2.z; a2.w += v2.w;
        a3.x += v3.x; a3.y += v3.y; a3.z += v3.z; a3.w += v3.w;
    }
    for (; e < e1; e++) {
        int s = csr[e];
        float4 v = h4_to_f4(hw2[(size_t)s * 16 + f4]);
        a0.x += v.x; a0.y += v.y; a0.z += v.z; a0.w += v.w;
    }
    float4 acc;
    acc.x = (a0.x + a1.x) + (a2.x + a3.x);
    acc.y = (a0.y + a1.y) + (a2.y + a3.y);
    acc.z = (a0.z + a1.z) + (a2.z + a3.z);
    acc.w = (a0.w + a1.w) + (a2.w + a3.w);

    float di = dinv[n];
    float4 b = bias4[f4], g = gamma4[f4], bt = beta4[f4], mn = mean4[f4], vr = var4[f4];
    float4 r;
    r.x = fmaxf((acc.x * di + b.x - mn.x) * (1.0f / sqrtf(vr.x + EPSBN)) * g.x + bt.x, 0.f);
    r.y = fmaxf((acc.y * di + b.y - mn.y) * (1.0f / sqrtf(vr.y + EPSBN)) * g.y + bt.y, 0.f);
    r.z = fmaxf((acc.z * di + b.z - mn.z) * (1.0f / sqrtf(vr.z + EPSBN)) * g.z + bt.z, 0.f);
    r.w = fmaxf((acc.w * di + b.w - mn.w) * (1.0f / sqrtf(vr.w + EPSBN)) * g.w + bt.w, 0.f);
    if (residual) {
        float4 hp = h[(size_t)n * 16 + f4];
        r.x += hp.x; r.y += hp.y; r.z += hp.z; r.w += hp.w;
    }
    h[(size_t)n * 16 + f4] = r;
}

// ---------------- pooling ----------------

__global__ void graph_ranges(const int* __restrict__ batch, int* __restrict__ gs,
                             int* __restrict__ ge, int N) {
    int i = blockIdx.x * blockDim.x + threadIdx.x;
    if (i >= N) return;
    int b = batch[i];
    if (i == 0 || batch[i - 1] != b) gs[b] = i;
    if (i == N - 1 || batch[i + 1] != b) ge[b] = i + 1;
}

__global__ void pool(const float4* __restrict__ h4, const int* __restrict__ gs,
                     const int* __restrict__ ge, float* __restrict__ pooled) {
    __shared__ float4 ssum[256], smax[256];
    int g = blockIdx.x;
    int tid = threadIdx.x;
    int f4 = tid & 15, c = tid >> 4;
    int s = gs[g], e = ge[g];
    float4 sum = make_float4(0.f, 0.f, 0.f, 0.f);
    float4 mx = make_float4(-FLT_MAX, -FLT_MAX, -FLT_MAX, -FLT_MAX);
    for (int i = s + c; i < e; i += 16) {
        float4 v = h4[(size_t)i * 16 + f4];
        sum.x += v.x; sum.y += v.y; sum.z += v.z; sum.w += v.w;
        mx.x = fmaxf(mx.x, v.x); mx.y = fmaxf(mx.y, v.y);
        mx.z = fmaxf(mx.z, v.z); mx.w = fmaxf(mx.w, v.w);
    }
    ssum[tid] = sum;
    smax[tid] = mx;
    __syncthreads();
    for (int half = 8; half >= 1; half >>= 1) {
        if (c < half) {
            int o = tid + half * 16;
            ssum[tid].x += ssum[o].x; ssum[tid].y += ssum[o].y;
            ssum[tid].z += ssum[o].z; ssum[tid].w += ssum[o].w;
            smax[tid].x = fmaxf(smax[tid].x, smax[o].x);
            smax[tid].y = fmaxf(smax[tid].y, smax[o].y);
            smax[tid].z = fmaxf(smax[tid].z, smax[o].z);
            smax[tid].w = fmaxf(smax[tid].w, smax[o].w);
        }
        __syncthreads();
    }
    if (c == 0) {
        float inv = 1.0f / (float)(e - s);
        float4 S = ssum[tid], M = smax[tid];
        float4 mean4 = make_float4(S.x * inv, S.y * inv, S.z * inv, S.w * inv);
        ((float4*)pooled)[(size_t)g * 32 + f4] = mean4;
        ((float4*)pooled)[(size_t)g * 32 + 16 + f4] = M;
    }
}

// ---------------- MLP head, fused per graph ----------------

__global__ void mlp(const float* __restrict__ pooled,
                    const float* __restrict__ W1, const float* __restrict__ b1,
                    const float* __restrict__ W2, const float* __restrict__ b2,
                    const float* __restrict__ Wg, const float* __restrict__ bg,
                    const float* __restrict__ Wb, const float* __restrict__ bb,
                    float* __restrict__ out) {
    __shared__ float in_s[128], h1[128], h2[64];
    int g = blockIdx.x, tid = threadIdx.x;
    in_s[tid] = pooled[g * 128 + tid];
    __syncthreads();
    float acc = b1[tid];
#pragma unroll 8
    for (int k = 0; k < 128; k++) acc += in_s[k] * W1[k * 128 + tid];
    h1[tid] = fmaxf(acc, 0.0f);
    __syncthreads();
    if (tid < 64) {
        float a2 = b2[tid];
#pragma unroll 8
        for (int k = 0; k < 128; k++) a2 += h1[k] * W2[k * 64 + tid];
        h2[tid] = fmaxf(a2, 0.0f);
    }
    __syncthreads();
    if (tid < 2) {
        const float* Wv = (tid == 0) ? Wg : Wb;
        float a = (tid == 0) ? bg[0] : bb[0];
        for (int k = 0; k < 64; k++) a += h2[k] * Wv[k];
        out[g * 2 + tid] = a;
    }
}

// ---------------- launch ----------------

extern "C" void kernel_launch(void* const* d_in, const int* in_sizes, int n_in,
                              void* d_out, int out_size, void* d_ws, size_t ws_size,
                              hipStream_t stream) {
    const float* x    = (const float*)d_in[0];
    const int*   ei   = (const int*)d_in[1];
    const int*   batch= (const int*)d_in[2];
    const float* W0   = (const float*)d_in[3];
    const float* b0   = (const float*)d_in[4];
    const float* Wh   = (const float*)d_in[5];
    const float* bh   = (const float*)d_in[6];
    const float* bng  = (const float*)d_in[7];
    const float* bnb  = (const float*)d_in[8];
    const float* bnm  = (const float*)d_in[9];
    const float* bnv  = (const float*)d_in[10];
    const float* fc1W = (const float*)d_in[11];
    const float* fc1b = (const float*)d_in[12];
    const float* fc2W = (const float*)d_in[13];
    const float* fc2b = (const float*)d_in[14];
    const float* fcgW = (const float*)d_in[15];
    const float* fcgb = (const float*)d_in[16];
    const float* fcbW = (const float*)d_in[17];
    const float* fcbb = (const float*)d_in[18];
    float* out = (float*)d_out;

    const int N = in_sizes[0] / 3;
    const int E = in_sizes[1] / 2;
    const int G = out_size / 2;
    const int* src = ei;
    const int* dst = ei + E;

    char* ws = (char*)d_ws;
    auto alloc = [&](size_t bytes) {
        char* p = ws;
        ws += (bytes + 255) & ~(size_t)255;
        return p;
    };
    int*    deg    = (int*)alloc((size_t)N * 4);
    int*    cur    = (int*)alloc((size_t)N * 4);
    float*  dinv   = (float*)alloc((size_t)N * 4);
    int*    offs   = (int*)alloc((size_t)(N + 1) * 4);
    int*    bsum   = (int*)alloc(512 * 4);
    int*    boff   = (int*)alloc(512 * 4);
    int*    csr    = (int*)alloc((size_t)E * 4);
    float*  h      = (float*)alloc((size_t)N * 64 * 4);
    __half* hw     = (__half*)alloc((size_t)N * 64 * 2);
    int*    gs     = (int*)alloc((size_t)G * 4);
    int*    ge     = (int*)alloc((size_t)G * 4);
    float*  pooled = (float*)alloc((size_t)G * 128 * 4);

    const int B = 256;
    int nbScan = (N + 255) / 256;
    const int S = 512;                 // edge stripes per dst-range partition
    const int partBlocks = 8 * S;      // blockIdx&7 = dst-range, blockIdx>>3 = stripe

    zero_two<<<(N + B - 1) / B, B, 0, stream>>>(deg, cur, N);
    count_deg_part<<<partBlocks, B, 0, stream>>>(dst, deg, E, N, S);
    calc_dinv<<<(N + B - 1) / B, B, 0, stream>>>(deg, dinv, N);
    scanA<<<nbScan, 256, 0, stream>>>(deg, offs, bsum, N);
    scanB<<<1, 512, 0, stream>>>(bsum, boff, nbScan);
    scanC<<<(N + B - 1) / B, B, 0, stream>>>(offs, boff, N, E);
    scatter_edges_part<<<partBlocks, B, 0, stream>>>(src, dst, offs, cur, csr, E, N, S);

    int aggBlocks = (N + 15) / 16;     // 16 nodes per block (16 lanes/node)

    // layer 0
    mm_in3<<<((size_t)N * 64 + B - 1) / B, B, 0, stream>>>(x, W0, dinv, hw, N);
    agg_bn<<<aggBlocks, 256, 0, stream>>>((const uint2*)hw, (float4*)h, dinv, csr, offs,
                                          (const float4*)b0,
                                          (const float4*)bng, (const float4*)bnb,
                                          (const float4*)bnm, (const float4*)bnv, 0, N);
    // layer 1
    mm64_reg<<<1024, 256, 0, stream>>>(h, Wh, dinv, hw, N);
    agg_bn<<<aggBlocks, 256, 0, stream>>>((const uint2*)hw, (float4*)h, dinv, csr, offs,
                                          (const float4*)(bh),
                                          (const float4*)(bng + 64), (const float4*)(bnb + 64),
                                          (const float4*)(bnm + 64), (const float4*)(bnv + 64), 1, N);
    // layer 2
    mm64_reg<<<1024, 256, 0, stream>>>(h, Wh + 4096, dinv, hw, N);
    agg_bn<<<aggBlocks, 256, 0, stream>>>((const uint2*)hw, (float4*)h, dinv, csr, offs,
                                          (const float4*)(bh + 64),
                                          (const float4*)(bng + 128), (const float4*)(bnb + 128),
                                          (const float4*)(bnm + 128), (const float4*)(bnv + 128), 1, N);

    // pooling + head
    graph_ranges<<<(N + B - 1) / B, B, 0, stream>>>(batch, gs, ge, N);
    pool<<<G, 256, 0, stream>>>((const float4*)h, gs, ge, pooled);
    mlp<<<G, 128, 0, stream>>>(pooled, fc1W, fc1b, fc2W, fc2b,
                               fcgW, fcgb, fcbW, fcbb, out);
}